// Round 9
// baseline (187.486 us; speedup 1.0000x reference)
//
#include <hip/hip_runtime.h>
#include <hip/hip_bf16.h>
#include <stdint.h>

// BertAttention (feature-axis attention), algebraically restructured:
//   G = x^T x  [D,D];  m = colsum(x);  u2 = Wq m + S*bq;  w = Wk m
//   scores = (Wq G Wk^T + u2 bk^T + bq w^T)/sqrt(D); attn = softmax(scores)
//   out = x (Wv^T attn) + 1 (bv^T attn)
// G: 256x256 8-wave counted-vmcnt engine, block-cooperative f16 epilogue.
// out: 128x512-tile engine (2 column groups -> x16 L3 re-reads 8x -> 2x).
// Small 1024^3 GEMMs: split-K4 128^2 engine + reduce_cast.

#define S_ 16384
#define D_ 1024

typedef _Float16 half8 __attribute__((ext_vector_type(8)));
typedef _Float16 half4 __attribute__((ext_vector_type(4)));
typedef float f32x4 __attribute__((ext_vector_type(4)));

__device__ __forceinline__ void gload_lds16(const _Float16* g, _Float16* l) {
    __builtin_amdgcn_global_load_lds(
        (const __attribute__((address_space(1))) void*)g,
        (__attribute__((address_space(3))) void*)l, 16, 0, 0);
}

#define VM8() do { asm volatile("s_waitcnt vmcnt(8)" ::: "memory"); __builtin_amdgcn_sched_barrier(0); } while (0)
#define VM5() do { asm volatile("s_waitcnt vmcnt(5)" ::: "memory"); __builtin_amdgcn_sched_barrier(0); } while (0)
#define VM0() do { asm volatile("s_waitcnt vmcnt(0)" ::: "memory"); __builtin_amdgcn_sched_barrier(0); } while (0)
#define BAR() __builtin_amdgcn_s_barrier()
#define LGKM0() do { asm volatile("s_waitcnt lgkmcnt(0)" ::: "memory"); __builtin_amdgcn_sched_barrier(0); } while (0)
#define LGKM8() do { asm volatile("s_waitcnt lgkmcnt(8)" ::: "memory"); __builtin_amdgcn_sched_barrier(0); } while (0)
#define PRIO1() __builtin_amdgcn_s_setprio(1)
#define PRIO0() __builtin_amdgcn_s_setprio(0)

// ====================================================== gemm256 (G only)
#define STAGEA(H, KT, NX) do { \
    const _Float16* _s = srcA + (size_t)((H) * 128) * lda + (size_t)(KT) * 64; \
    _Float16* _d = AsS + (NX) * 16384 + ((H) * 128 + 8 * w) * 64; \
    gload_lds16(_s, _d); \
    gload_lds16(_s + (size_t)64 * lda, _d + 4096); \
} while (0)

#define STAGEB(H, KT, NX) do { \
    const _Float16* _s = srcB + (size_t)((H) * 128) * ldb + (size_t)(KT) * 64; \
    _Float16* _d = BsS + (NX) * 16384 + ((H) * 128 + 8 * w) * 64; \
    gload_lds16(_s, _d); \
    gload_lds16(_s + (size_t)64 * ldb, _d + 4096); \
} while (0)

#define READA(PA, QA) do { _Pragma("unroll") \
    for (int fm = 0; fm < 4; ++fm) { \
        af[fm][0] = *(const half8*)((PA) + (((QA) * 128 + fm * 16) << 7) + cx0); \
        af[fm][1] = *(const half8*)((PA) + (((QA) * 128 + fm * 16) << 7) + cx1); } \
} while (0)

#define READB(PB, BF, QB) do { _Pragma("unroll") \
    for (int fn = 0; fn < 2; ++fn) { \
        BF[fn][0] = *(const half8*)((PB) + (((QB) * 128 + fn * 16) << 7) + cx0); \
        BF[fn][1] = *(const half8*)((PB) + (((QB) * 128 + fn * 16) << 7) + cx1); } \
} while (0)

#define MFMAB(QA, QB, BF) do { _Pragma("unroll") \
    for (int fm = 0; fm < 4; ++fm) { _Pragma("unroll") \
        for (int fn = 0; fn < 2; ++fn) { \
            f32x4 _c = acc[(QA) * 4 + fm][(QB) * 2 + fn]; \
            _c = __builtin_amdgcn_mfma_f32_16x16x32_f16(af[fm][0], BF[fn][0], _c, 0, 0, 0); \
            _c = __builtin_amdgcn_mfma_f32_16x16x32_f16(af[fm][1], BF[fn][1], _c, 0, 0, 0); \
            acc[(QA) * 4 + fm][(QB) * 2 + fn] = _c; } } \
} while (0)

// f16-out, split-K partials. Used for G = xT xT^T.
__global__ __launch_bounds__(512, 2)
void gemm256(const _Float16* __restrict__ A, const _Float16* __restrict__ B,
             _Float16* __restrict__ C,
             int lda, int ldb, int ldc, int ksub, long long mn,
             int ntx, int ntxy, int cpx) {
    __shared__ _Float16 SM2[65536];   // 128KB: As 2x16384, Bs 2x16384
    _Float16* AsS = SM2;
    _Float16* BsS = SM2 + 32768;
    const int t = threadIdx.x;
    const int l = t & 63;
    const int w = t >> 6;
    const int wm = w >> 2, wn = w & 3;

    const int hb = blockIdx.x;
    const int lg = (hb & 7) * cpx + (hb >> 3);
    const int bz = lg / ntxy;
    const int rem = lg - bz * ntxy;
    const int by = rem / ntx;
    const int bx = rem - by * ntx;
    const size_t m0 = (size_t)by * 256;
    const size_t n0 = (size_t)bx * 256;
    const size_t k0 = (size_t)bz * (size_t)ksub;
    const long long coff = (long long)bz * mn;

    const int colsw = 8 * ((l & 7) ^ (l >> 3));
    const _Float16* srcA = A + (m0 + 8 * w + (l >> 3)) * (size_t)lda + k0 + colsw;
    const _Float16* srcB = B + (n0 + 8 * w + (l >> 3)) * (size_t)ldb + k0 + colsw;

    const int cx0 = (((l >> 4) << 4)) ^ ((l & 7) << 4);
    const int cx1 = (64 + ((l >> 4) << 4)) ^ ((l & 7) << 4);
    const char* basePA = (const char*)AsS + ((wm * 64 + (l & 15)) << 7);
    const char* basePB = (const char*)BsS + ((wn * 32 + (l & 15)) << 7);

    f32x4 acc[8][4] = {};
    half8 af[4][2], bf0[2][2], bf1[2][2];

    const int nk = ksub >> 6;

    STAGEA(0, 0, 0); STAGEB(0, 0, 0); STAGEB(1, 0, 0); STAGEA(1, 0, 0);
    STAGEA(0, 1, 1); STAGEB(0, 1, 1); STAGEB(1, 1, 1); STAGEA(1, 1, 1);

    for (int kt = 0; kt < nk; ++kt) {
        const int p = kt & 1;
        const int ks = kt + 2;
        const bool hs = ks < nk;
        const char* pA = basePA + p * 32768;
        const char* pB = basePB + p * 32768;

        if (kt == nk - 1) VM0(); else VM8();
        BAR();

        READA(pA, 0); READB(pB, bf0, 0);
        LGKM8();
        BAR(); LGKM0();
        PRIO1(); MFMAB(0, 0, bf0); PRIO0(); BAR();

        READB(pB, bf1, 1);
        if (hs) { STAGEA(0, ks, p); STAGEB(0, ks, p); }
        BAR(); LGKM0();
        PRIO1(); MFMAB(0, 1, bf1); PRIO0(); BAR();

        READA(pA, 1);
        if (hs) STAGEB(1, ks, p);
        BAR(); LGKM0();
        PRIO1(); MFMAB(1, 1, bf1); PRIO0(); BAR();

        if (hs) STAGEA(1, ks, p);
        PRIO1(); MFMAB(1, 0, bf0); PRIO0(); BAR();
    }

    // block-cooperative f16 epilogue: [128][264] LDS restage -> 512B segments
    _Float16* eb = SM2;
    const int cr = (l >> 4) << 2;
    const int cc = l & 15;
#pragma unroll
    for (int h = 0; h < 2; ++h) {
        BAR();
#pragma unroll
        for (int mm = 0; mm < 4; ++mm) {
#pragma unroll
            for (int n = 0; n < 4; ++n) {
                const int lrow0 = wm * 64 + mm * 16 + cr;
                const int lcol = (n >> 1) * 128 + wn * 32 + (n & 1) * 16 + cc;
#pragma unroll
                for (int r = 0; r < 4; ++r)
                    eb[(lrow0 + r) * 264 + lcol] = (_Float16)acc[h * 4 + mm][n][r];
            }
        }
        LGKM0();
        BAR();
        // readback: wave w owns rows [w*16, w*16+16); 512B per half-wave
#pragma unroll
        for (int i = 0; i < 8; ++i) {
            const int lrow = w * 16 + i * 2 + (l >> 5);
            const half8 v = *(const half8*)(eb + lrow * 264 + (l & 31) * 8);
            const size_t row = m0 + (size_t)h * 128 + lrow;
            const size_t col = n0 + (l & 31) * 8;
            __builtin_nontemporal_store(v,
                (half8*)(C + coff + (long long)row * ldc + col));
        }
        LGKM0();
    }
}

// ===================== gemm_out: out = x16 * MT^T + colbias (fp32 out) ====
// BM=128, BN=512, BK=32, 8 waves (2m x 4n; per-wave 64x128 = 4x8 frags).
// 80KB LDS. Ledger: 5 loads/wave/tile, VM5/tile. 2 sub-phases: {read+MFMA
// half, BAR} {stage kt+2, MFMA half, BAR}. Only 2 column groups -> x16 L3
// traffic 67MB (was 268MB at BN=128). LDS-staged 512B-segment epilogue.
#define STGO(KT, NX) do { \
    const _Float16* _sa = srcA + (size_t)(KT) * 32; \
    gload_lds16(_sa, AsS + (NX) * 4096 + w * 512); \
    const _Float16* _sb = srcB + (size_t)(KT) * 32; \
    _Float16* _db = BsS + (NX) * 16384 + w * 2048; \
    gload_lds16(_sb, _db); \
    gload_lds16(_sb + 16 * 1024, _db + 512); \
    gload_lds16(_sb + 32 * 1024, _db + 1024); \
    gload_lds16(_sb + 48 * 1024, _db + 1536); \
} while (0)

__global__ __launch_bounds__(512, 2)
void gemm_out(const _Float16* __restrict__ A, const _Float16* __restrict__ B,
              float* __restrict__ C, const float* __restrict__ bias) {
    __shared__ _Float16 SM[40960];   // As 2x4096 (16KB) + Bs 2x16384 (64KB)
    _Float16* AsS = SM;
    _Float16* BsS = SM + 8192;
    const int t = threadIdx.x;
    const int l = t & 63;
    const int w = t >> 6;
    const int wm = w >> 2, wn = w & 3;

    // XCD swizzle; bx = lg&1 so both column-groups of a row-panel co-locate
    const int hb = blockIdx.x;
    const int lg = (hb & 7) * 32 + (hb >> 3);
    const int by = lg >> 1;
    const int bx = lg & 1;
    const size_t m0 = (size_t)by * 128;
    const size_t n0 = (size_t)bx * 512;

    // stage source: rows l>>2 within 16-row group; col pre-swizzled (64B rows)
    const int colsw = 8 * ((l & 3) ^ ((l >> 2) & 3));
    const _Float16* srcA = A + (m0 + w * 16 + (l >> 2)) * (size_t)1024 + colsw;
    const _Float16* srcB = B + (n0 + w * 64 + (l >> 2)) * (size_t)1024 + colsw;

    // read-side swizzle: frag row rr has rr&3 == l&3; k-slice s = l>>4
    const int cx = (((l >> 4) ^ (l & 3)) << 4);
    const char* basePA = (const char*)AsS + ((wm * 64 + (l & 15)) << 6) + cx;
    const char* basePB = (const char*)BsS + ((wn * 128 + (l & 15)) << 6) + cx;

    f32x4 acc[4][8] = {};
    half8 af[4], bf[8];

    const int nk = 32;   // K=1024, BK=32

    STGO(0, 0);
    STGO(1, 1);

    for (int kt = 0; kt < nk; ++kt) {
        const int p = kt & 1;
        const int ks = kt + 2;
        const bool hs = ks < nk;
        const char* pA = basePA + p * 8192;
        const char* pB = basePB + p * 32768;

        if (kt == nk - 1) VM0(); else VM5();
        BAR();

        // read all fragments (12 ds_read_b128)
#pragma unroll
        for (int fm = 0; fm < 4; ++fm)
            af[fm] = *(const half8*)(pA + fm * 1024);
#pragma unroll
        for (int fn = 0; fn < 8; ++fn)
            bf[fn] = *(const half8*)(pB + fn * 1024);
        LGKM0();
        PRIO1();
#pragma unroll
        for (int fm = 0; fm < 4; ++fm)
#pragma unroll
            for (int fn = 0; fn < 4; ++fn)
                acc[fm][fn] = __builtin_amdgcn_mfma_f32_16x16x32_f16(af[fm], bf[fn], acc[fm][fn], 0, 0, 0);
        PRIO0();
        BAR();   // all waves' reads of buf p retired

        if (hs) STGO(ks, p);
        PRIO1();
#pragma unroll
        for (int fm = 0; fm < 4; ++fm)
#pragma unroll
            for (int fn = 4; fn < 8; ++fn)
                acc[fm][fn] = __builtin_amdgcn_mfma_f32_16x16x32_f16(af[fm], bf[fn], acc[fm][fn], 0, 0, 0);
        PRIO0();
        BAR();
    }

    // epilogue: per-wave private [16][132] f32 LDS; 512B store segments
    float* lw = (float*)SM + w * 2112;
    const int cr = (l >> 4) << 2;
    const int cc = l & 15;
    float bb[8];
#pragma unroll
    for (int fn = 0; fn < 8; ++fn)
        bb[fn] = bias[n0 + wn * 128 + fn * 16 + cc];
#pragma unroll
    for (int mm = 0; mm < 4; ++mm) {
#pragma unroll
        for (int fn = 0; fn < 8; ++fn) {
            const int lcol = fn * 16 + cc;
#pragma unroll
            for (int r = 0; r < 4; ++r)
                lw[(cr + r) * 132 + lcol] = acc[mm][fn][r] + bb[fn];
        }
        LGKM0();
#pragma unroll
        for (int i = 0; i < 8; ++i) {
            const int lrow = i * 2 + (l >> 5);
            const f32x4 v = *(const f32x4*)(lw + lrow * 132 + (l & 31) * 4);
            const size_t row = m0 + wm * 64 + mm * 16 + lrow;
            const size_t col = n0 + wn * 128 + (l & 31) * 4;
            __builtin_nontemporal_store(v, (f32x4*)(C + row * 1024 + col));
        }
        LGKM0();
    }
}

// ------------------------------------------------- 128^2 engine (small GEMMs)
__global__ __launch_bounds__(256, 2)
void gemm_abt(const _Float16* __restrict__ A, const _Float16* __restrict__ B,
              float* __restrict__ C, int lda, int ldb, int ldc, int ksub,
              long long mn) {
    const int t = threadIdx.x;
    const int lane = t & 63;
    const int wave = t >> 6;
    const int wr = (wave >> 1) * 64;
    const int wc = (wave & 1) * 64;
    const size_t m0 = (size_t)blockIdx.y * 128;
    const size_t n0 = (size_t)blockIdx.x * 128;
    const size_t k0 = (size_t)blockIdx.z * (size_t)ksub;
    const long long coff = (long long)blockIdx.z * mn;

    __shared__ _Float16 As[128 * 32];
    __shared__ _Float16 Bs[128 * 32];

    f32x4 acc[4][4] = {};

    const _Float16* a0 = A + (m0 + (size_t)(t >> 2)) * (size_t)lda + k0 + (t & 3) * 8;
    const _Float16* a1 = a0 + (size_t)64 * lda;
    const _Float16* b0 = B + (n0 + (size_t)(t >> 2)) * (size_t)ldb + k0 + (t & 3) * 8;
    const _Float16* b1 = b0 + (size_t)64 * ldb;
    _Float16* AsW0 = As + wave * 512;
    _Float16* AsW1 = As + 2048 + wave * 512;
    _Float16* BsW0 = Bs + wave * 512;
    _Float16* BsW1 = Bs + 2048 + wave * 512;

    const int nk = ksub >> 5;
    for (int kt = 0; kt < nk; ++kt) {
        __syncthreads();
        gload_lds16(a0, AsW0);
        gload_lds16(a1, AsW1);
        gload_lds16(b0, BsW0);
        gload_lds16(b1, BsW1);
        a0 += 32; a1 += 32; b0 += 32; b1 += 32;
        __syncthreads();

        half8 af[4], bf[4];
#pragma unroll
        for (int i = 0; i < 4; ++i)
            af[i] = *(const half8*)(As + (wr + i * 16 + (lane & 15)) * 32 + (lane >> 4) * 8);
#pragma unroll
        for (int i = 0; i < 4; ++i)
            bf[i] = *(const half8*)(Bs + (wc + i * 16 + (lane & 15)) * 32 + (lane >> 4) * 8);
#pragma unroll
        for (int i = 0; i < 4; ++i)
#pragma unroll
            for (int j = 0; j < 4; ++j)
                acc[i][j] = __builtin_amdgcn_mfma_f32_16x16x32_f16(af[i], bf[j], acc[i][j], 0, 0, 0);
    }

    const int cr = (lane >> 4) * 4;
    const int cc = lane & 15;
#pragma unroll
    for (int i = 0; i < 4; ++i) {
#pragma unroll
        for (int j = 0; j < 4; ++j) {
            const size_t row0 = m0 + wr + i * 16 + cr;
            const size_t col = n0 + wc + j * 16 + cc;
#pragma unroll
            for (int r = 0; r < 4; ++r)
                C[coff + (long long)(row0 + r) * ldc + col] = acc[i][j][r];
        }
    }
}

// ------------------------------------------------------------- prep kernels
template <int WRITE_ROW, int COLSUM>
__global__ __launch_bounds__(256)
void cast_transpose(const float* __restrict__ in, _Float16* __restrict__ outRow,
                    _Float16* __restrict__ outT, float* __restrict__ msum, int ldT) {
    __shared__ _Float16 tile[64][66];
    __shared__ float red[16][16][4];
    const int t = threadIdx.x;
    const int c0 = blockIdx.x * 64;
    const int r0 = blockIdx.y * 64;
    const int cg = t & 15;
    const int rb = t >> 4;
    f32x4 csum = {};
#pragma unroll
    for (int it = 0; it < 4; ++it) {
        const int rr = rb + it * 16;
        f32x4 v = *(const f32x4*)(in + (size_t)(r0 + rr) * 1024 + c0 + cg * 4);
        if (COLSUM) { csum[0] += v[0]; csum[1] += v[1]; csum[2] += v[2]; csum[3] += v[3]; }
        _Float16 h0 = (_Float16)v[0], h1 = (_Float16)v[1];
        _Float16 h2 = (_Float16)v[2], h3 = (_Float16)v[3];
        tile[rr][cg * 4 + 0] = h0; tile[rr][cg * 4 + 1] = h1;
        tile[rr][cg * 4 + 2] = h2; tile[rr][cg * 4 + 3] = h3;
        if (WRITE_ROW) {
            half4 h = {h0, h1, h2, h3};
            *(half4*)(outRow + (size_t)(r0 + rr) * 1024 + c0 + cg * 4) = h;
        }
    }
    if (COLSUM) {
        red[rb][cg][0] = csum[0]; red[rb][cg][1] = csum[1];
        red[rb][cg][2] = csum[2]; red[rb][cg][3] = csum[3];
    }
    __syncthreads();
    if (COLSUM && t < 64) {
        float s = 0.f;
#pragma unroll
        for (int k = 0; k < 16; ++k) s += red[k][t >> 2][t & 3];
        atomicAdd(msum + c0 + t, s);
    }
    const int i = t >> 2, ch = (t & 3) * 16;
    half8 h0v, h1v;
#pragma unroll
    for (int j = 0; j < 8; ++j) h0v[j] = tile[ch + j][i];
#pragma unroll
    for (int j = 0; j < 8; ++j) h1v[j] = tile[ch + 8 + j][i];
    *(half8*)(outT + (size_t)(c0 + i) * ldT + r0 + ch) = h0v;
    *(half8*)(outT + (size_t)(c0 + i) * ldT + r0 + ch + 8) = h1v;
}

// Fused weight prep: blocks [0,512) Wq cast + dot(m)->u2; [512,1024) Wk
// cast + dot(m)->w; [1024,1280) Wv transpose-cast.
__global__ __launch_bounds__(256)
void prep_w(const float* __restrict__ Wq, const float* __restrict__ Wk,
            const float* __restrict__ Wv, const float* __restrict__ bq,
            const float* __restrict__ m,
            _Float16* __restrict__ wq16, _Float16* __restrict__ wk16,
            _Float16* __restrict__ wvT16,
            float* __restrict__ u2, float* __restrict__ w) {
    __shared__ _Float16 tile[64][66];
    __shared__ float wred[4];
    const int b = blockIdx.x;
    const int t = threadIdx.x;

    if (b < 1024) {
        const bool isQ = b < 512;
        const int bb = isQ ? b : b - 512;
        const float* W = isQ ? Wq : Wk;
        _Float16* o = isQ ? wq16 : wk16;
        const size_t base = (size_t)bb * 2048 + (size_t)t * 8;
        const f32x4* p = (const f32x4*)(W + base);
        f32x4 x0 = p[0], x1 = p[1];
        half8 h;
        h[0] = (_Float16)x0[0]; h[1] = (_Float16)x0[1];
        h[2] = (_Float16)x0[2]; h[3] = (_Float16)x0[3];
        h[4] = (_Float16)x1[0]; h[5] = (_Float16)x1[1];
        h[6] = (_Float16)x1[2]; h[7] = (_Float16)x1[3];
        ((half8*)o)[bb * 256 + t] = h;
        const int col = (t * 8) & 1023;
        f32x4 m0 = *(const f32x4*)(m + col);
        f32x4 m1 = *(const f32x4*)(m + col + 4);
        float s = x0[0] * m0[0] + x0[1] * m0[1] + x0[2] * m0[2] + x0[3] * m0[3]
                + x1[0] * m1[0] + x1[1] * m1[1] + x1[2] * m1[2] + x1[3] * m1[3];
        for (int o2 = 32; o2; o2 >>= 1) s += __shfl_xor(s, o2);
        if ((t & 63) == 0) wred[t >> 6] = s;
        __syncthreads();
        if (t == 0) {
            const int rA = 2 * bb, rB = 2 * bb + 1;
            const float vA = wred[0] + wred[1];
            const float vB = wred[2] + wred[3];
            if (isQ) {
                u2[rA] = vA + 16384.0f * bq[rA];
                u2[rB] = vB + 16384.0f * bq[rB];
            } else {
                w[rA] = vA;
                w[rB] = vB;
            }
        }
        return;
    }

    const int bb = b - 1024;
    const int c0 = (bb & 15) * 64;
    const int r0 = (bb >> 4) * 64;
    const int cg = t & 15;
    const int rb = t >> 4;
#pragma unroll
    for (int it = 0; it < 4; ++it) {
        const int rr = rb + it * 16;
        f32x4 v = *(const f32x4*)(Wv + (size_t)(r0 + rr) * 1024 + c0 + cg * 4);
        tile[rr][cg * 4 + 0] = (_Float16)v[0];
        tile[rr][cg * 4 + 1] = (_Float16)v[1];
        tile[rr][cg * 4 + 2] = (_Float16)v[2];
        tile[rr][cg * 4 + 3] = (_Float16)v[3];
    }
    __syncthreads();
    const int i = t >> 2, ch = (t & 3) * 16;
    half8 h0v, h1v;
#pragma unroll
    for (int j = 0; j < 8; ++j) h0v[j] = tile[ch + j][i];
#pragma unroll
    for (int j = 0; j < 8; ++j) h1v[j] = tile[ch + 8 + j][i];
    *(half8*)(wvT16 + (size_t)(c0 + i) * 1024 + r0 + ch) = h0v;
    *(half8*)(wvT16 + (size_t)(c0 + i) * 1024 + r0 + ch + 8) = h1v;
}

__global__ void zero_vec(float* __restrict__ p, int n) {
    int i = blockIdx.x * 256 + threadIdx.x;
    if (i < n) p[i] = 0.f;
}

__global__ __launch_bounds__(256)
void reduce_g(const _Float16* __restrict__ part, _Float16* __restrict__ G16) {
    const size_t off = ((size_t)blockIdx.x * 256 + threadIdx.x) * 8;
    float s[8] = {};
    for (int z = 0; z < 16; ++z) {
        half8 v = *(const half8*)(part + (size_t)z * 1048576 + off);
#pragma unroll
        for (int j = 0; j < 8; ++j) s[j] += (float)v[j];
    }
    half8 o;
#pragma unroll
    for (int j = 0; j < 8; ++j) o[j] = (_Float16)s[j];
    *(half8*)(G16 + off) = o;
}

__global__ __launch_bounds__(256)
void reduce_cast(const float* __restrict__ part, _Float16* __restrict__ outh,
                 int nz, float scale) {
    const int idx = (blockIdx.x * 256 + threadIdx.x) * 4;
    f32x4 s = {};
    for (int z = 0; z < nz; ++z) {
        f32x4 v = *(const f32x4*)(part + (size_t)z * 1048576 + idx);
        s[0] += v[0]; s[1] += v[1]; s[2] += v[2]; s[3] += v[3];
    }
    half4 h;
    h[0] = (_Float16)(s[0] * scale); h[1] = (_Float16)(s[1] * scale);
    h[2] = (_Float16)(s[2] * scale); h[3] = (_Float16)(s[3] * scale);
    *(half4*)(outh + idx) = h;
}

// reduce 4 split-K fp32 slices + rank-1 terms + 1/32 scale + row-softmax
__global__ __launch_bounds__(256)
void softmax_rows(const float* __restrict__ part, const float* __restrict__ u2,
                  const float* __restrict__ bq, const float* __restrict__ bk,
                  const float* __restrict__ w,
                  float* __restrict__ P, _Float16* __restrict__ PT) {
    const int a = blockIdx.x;
    const int t = threadIdx.x;
    __shared__ float red[8];
    const size_t off = (size_t)a * 1024 + t * 4;
    f32x4 s = {};
#pragma unroll
    for (int z = 0; z < 4; ++z) {
        f32x4 v = *(const f32x4*)(part + (size_t)z * 1048576 + off);
        s[0] += v[0]; s[1] += v[1]; s[2] += v[2]; s[3] += v[3];
    }
    const float ru = u2[a], rb = bq[a];
    f32x4 bk4 = *(const f32x4*)(bk + t * 4);
    f32x4 w4 = *(const f32x4*)(w + t * 4);
#pragma unroll
    for (int j = 0; j < 4; ++j) s[j] = (s[j] + ru * bk4[j] + rb * w4[j]) * 0.03125f;

    float m = fmaxf(fmaxf(s[0], s[1]), fmaxf(s[2], s[3]));
    for (int o = 32; o; o >>= 1) m = fmaxf(m, __shfl_xor(m, o));
    if ((t & 63) == 0) red[t >> 6] = m;
    __syncthreads();
    m = fmaxf(fmaxf(red[0], red[1]), fmaxf(red[2], red[3]));

    float e0 = expf(s[0] - m), e1 = expf(s[1] - m);
    float e2 = expf(s[2] - m), e3 = expf(s[3] - m);
    float sum = e0 + e1 + e2 + e3;
    for (int o = 32; o; o >>= 1) sum += __shfl_xor(sum, o);
    if ((t & 63) == 0) red[4 + (t >> 6)] = sum;
    __syncthreads();
    sum = red[4] + red[5] + red[6] + red[7];
    const float inv = 1.0f / sum;

    f32x4 o4 = {e0 * inv, e1 * inv, e2 * inv, e3 * inv};
    *(f32x4*)(P + off) = o4;
    const int b = t * 4;
    PT[(size_t)(b + 0) * 1024 + a] = (_Float16)o4[0];
    PT[(size_t)(b + 1) * 1024 + a] = (_Float16)o4[1];
    PT[(size_t)(b + 2) * 1024 + a] = (_Float16)o4[2];
    PT[(size_t)(b + 3) * 1024 + a] = (_Float16)o4[3];
}

__global__ __launch_bounds__(256)
void attn_bv(const float* __restrict__ attn, const float* __restrict__ bv,
             float* __restrict__ c) {
    const int j = blockIdx.x * 256 + threadIdx.x;
    const int a0 = blockIdx.y * 64;
    float s = 0.f;
#pragma unroll 4
    for (int k = 0; k < 64; ++k) {
        const int a = a0 + k;
        s += attn[(size_t)a * 1024 + j] * bv[a];
    }
    atomicAdd(c + j, s);
}

extern "C" void kernel_launch(void* const* d_in, const int* in_sizes, int n_in,
                              void* d_out, int out_size, void* d_ws, size_t ws_size,
                              hipStream_t stream) {
    const float* x  = (const float*)d_in[0];
    const float* Wq = (const float*)d_in[1];
    const float* bq = (const float*)d_in[2];
    const float* Wk = (const float*)d_in[3];
    const float* bk = (const float*)d_in[4];
    const float* Wv = (const float*)d_in[5];
    const float* bv = (const float*)d_in[6];
    float* out  = (float*)d_out;                   // [S,D] fp32
    float* attn = out + (size_t)S_ * D_;           // [D,D] fp32

    char* ws = (char*)d_ws;
    float*    part  = (float*)ws;                          // 32MB, reused
    _Float16* partH = (_Float16*)ws;                       // G f16 partials
    _Float16* x16   = (_Float16*)(ws + 33554432);          // [S,D]   33.5MB
    _Float16* xT16  = (_Float16*)(ws + 67108864);          // [D,S]   33.5MB
    _Float16* wq16  = (_Float16*)(ws + 100663296);         // [D,D]   2MB
    _Float16* wk16  = (_Float16*)(ws + 102760448);
    _Float16* wvT16 = (_Float16*)(ws + 104857600);
    _Float16* G16   = (_Float16*)(ws + 106954752);
    _Float16* U16   = (_Float16*)(ws + 109051904);
    _Float16* PT    = (_Float16*)(ws + 111149056);
    _Float16* MT16  = (_Float16*)(ws + 113246208);
    float*    mvec  = (float*)(ws + 115343360);            // m, u2, w, c
    float*    u2    = mvec + 1024;
    float*    wv    = u2 + 1024;
    float*    cvec  = wv + 1024;

    zero_vec<<<16, 256, 0, stream>>>(mvec, 4096);
    cast_transpose<1, 1><<<dim3(16, 256), 256, 0, stream>>>(x, x16, xT16, mvec, S_);
    prep_w<<<1280, 256, 0, stream>>>(Wq, Wk, Wv, bq, mvec,
                                     wq16, wk16, wvT16, u2, wv);

    // G = xT * xT^T  (M=N=1024, K=16384, split-K 16, f16 partials)
    gemm256<<<256, 512, 0, stream>>>(xT16, xT16, partH,
                                     16384, 16384, 1024, 1024, 1048576LL,
                                     4, 16, 32);
    reduce_g<<<512, 256, 0, stream>>>(partH, G16);
    // U = Wq * G  (split-K4, fp32 partials)
    gemm_abt<<<dim3(8, 8, 4), 256, 0, stream>>>(wq16, G16, part,
                                                1024, 1024, 1024, 256, 1048576);
    reduce_cast<<<1024, 256, 0, stream>>>(part, U16, 4, 1.0f);
    // scores partials = U * Wk^T (split-K4; rank-1 + scale fused in softmax)
    gemm_abt<<<dim3(8, 8, 4), 256, 0, stream>>>(U16, wk16, part,
                                                1024, 1024, 1024, 256, 1048576);
    softmax_rows<<<1024, 256, 0, stream>>>(part, u2, bq, bk, wv, attn, PT);
    attn_bv<<<dim3(4, 16), 256, 0, stream>>>(attn, bv, cvec);
    // MT[j,i] = sum_a attn[a,j] Wv[a,i]  (split-K4)
    gemm_abt<<<dim3(8, 8, 4), 256, 0, stream>>>(PT, wvT16, part,
                                                1024, 1024, 1024, 256, 1048576);
    reduce_cast<<<1024, 256, 0, stream>>>(part, MT16, 4, 1.0f);
    // out = x16 * MT^T + cvec  (BM=128 x BN=512; 256 blocks)
    gemm_out<<<256, 512, 0, stream>>>(x16, MT16, out, cvec);
}

// Round 10
// 182.990 us; speedup vs baseline: 1.0246x; 1.0246x over previous
//
#include <hip/hip_runtime.h>
#include <hip/hip_bf16.h>
#include <stdint.h>

// BertAttention (feature-axis attention), algebraically restructured:
//   G = x^T x  [D,D];  m = colsum(x);  u2 = Wq m + S*bq;  w = Wk m
//   scores = (Wq G Wk^T + u2 bk^T + bq w^T)/sqrt(D); attn = softmax(scores)
//   out = x (Wv^T attn) + 1 (bv^T attn)
// G: 256x256 8-wave counted-vmcnt engine + block-cooperative f16 epilogue
// (round-9 win). out: 128x128 gemm128, 2 blk/CU (round-8 best). Small
// 1024^3 GEMMs: split-K4 128^2 engine + reduce_cast.

#define S_ 16384
#define D_ 1024

typedef _Float16 half8 __attribute__((ext_vector_type(8)));
typedef _Float16 half4 __attribute__((ext_vector_type(4)));
typedef float f32x4 __attribute__((ext_vector_type(4)));

__device__ __forceinline__ void gload_lds16(const _Float16* g, _Float16* l) {
    __builtin_amdgcn_global_load_lds(
        (const __attribute__((address_space(1))) void*)g,
        (__attribute__((address_space(3))) void*)l, 16, 0, 0);
}

#define VM8() do { asm volatile("s_waitcnt vmcnt(8)" ::: "memory"); __builtin_amdgcn_sched_barrier(0); } while (0)
#define VM0() do { asm volatile("s_waitcnt vmcnt(0)" ::: "memory"); __builtin_amdgcn_sched_barrier(0); } while (0)
#define BAR() __builtin_amdgcn_s_barrier()
#define LGKM0() do { asm volatile("s_waitcnt lgkmcnt(0)" ::: "memory"); __builtin_amdgcn_sched_barrier(0); } while (0)
#define LGKM8() do { asm volatile("s_waitcnt lgkmcnt(8)" ::: "memory"); __builtin_amdgcn_sched_barrier(0); } while (0)
#define PRIO1() __builtin_amdgcn_s_setprio(1)
#define PRIO0() __builtin_amdgcn_s_setprio(0)

// ====================================================== gemm256 (G only)
#define STAGEA(H, KT, NX) do { \
    const _Float16* _s = srcA + (size_t)((H) * 128) * lda + (size_t)(KT) * 64; \
    _Float16* _d = AsS + (NX) * 16384 + ((H) * 128 + 8 * w) * 64; \
    gload_lds16(_s, _d); \
    gload_lds16(_s + (size_t)64 * lda, _d + 4096); \
} while (0)

#define STAGEB(H, KT, NX) do { \
    const _Float16* _s = srcB + (size_t)((H) * 128) * ldb + (size_t)(KT) * 64; \
    _Float16* _d = BsS + (NX) * 16384 + ((H) * 128 + 8 * w) * 64; \
    gload_lds16(_s, _d); \
    gload_lds16(_s + (size_t)64 * ldb, _d + 4096); \
} while (0)

#define READA(PA, QA) do { _Pragma("unroll") \
    for (int fm = 0; fm < 4; ++fm) { \
        af[fm][0] = *(const half8*)((PA) + (((QA) * 128 + fm * 16) << 7) + cx0); \
        af[fm][1] = *(const half8*)((PA) + (((QA) * 128 + fm * 16) << 7) + cx1); } \
} while (0)

#define READB(PB, BF, QB) do { _Pragma("unroll") \
    for (int fn = 0; fn < 2; ++fn) { \
        BF[fn][0] = *(const half8*)((PB) + (((QB) * 128 + fn * 16) << 7) + cx0); \
        BF[fn][1] = *(const half8*)((PB) + (((QB) * 128 + fn * 16) << 7) + cx1); } \
} while (0)

#define MFMAB(QA, QB, BF) do { _Pragma("unroll") \
    for (int fm = 0; fm < 4; ++fm) { _Pragma("unroll") \
        for (int fn = 0; fn < 2; ++fn) { \
            f32x4 _c = acc[(QA) * 4 + fm][(QB) * 2 + fn]; \
            _c = __builtin_amdgcn_mfma_f32_16x16x32_f16(af[fm][0], BF[fn][0], _c, 0, 0, 0); \
            _c = __builtin_amdgcn_mfma_f32_16x16x32_f16(af[fm][1], BF[fn][1], _c, 0, 0, 0); \
            acc[(QA) * 4 + fm][(QB) * 2 + fn] = _c; } } \
} while (0)

// f16-out, split-K partials. Used for G = xT xT^T.
__global__ __launch_bounds__(512, 2)
void gemm256(const _Float16* __restrict__ A, const _Float16* __restrict__ B,
             _Float16* __restrict__ C,
             int lda, int ldb, int ldc, int ksub, long long mn,
             int ntx, int ntxy, int cpx) {
    __shared__ _Float16 SM2[65536];   // 128KB: As 2x16384, Bs 2x16384
    _Float16* AsS = SM2;
    _Float16* BsS = SM2 + 32768;
    const int t = threadIdx.x;
    const int l = t & 63;
    const int w = t >> 6;
    const int wm = w >> 2, wn = w & 3;

    const int hb = blockIdx.x;
    const int lg = (hb & 7) * cpx + (hb >> 3);
    const int bz = lg / ntxy;
    const int rem = lg - bz * ntxy;
    const int by = rem / ntx;
    const int bx = rem - by * ntx;
    const size_t m0 = (size_t)by * 256;
    const size_t n0 = (size_t)bx * 256;
    const size_t k0 = (size_t)bz * (size_t)ksub;
    const long long coff = (long long)bz * mn;

    const int colsw = 8 * ((l & 7) ^ (l >> 3));
    const _Float16* srcA = A + (m0 + 8 * w + (l >> 3)) * (size_t)lda + k0 + colsw;
    const _Float16* srcB = B + (n0 + 8 * w + (l >> 3)) * (size_t)ldb + k0 + colsw;

    const int cx0 = (((l >> 4) << 4)) ^ ((l & 7) << 4);
    const int cx1 = (64 + ((l >> 4) << 4)) ^ ((l & 7) << 4);
    const char* basePA = (const char*)AsS + ((wm * 64 + (l & 15)) << 7);
    const char* basePB = (const char*)BsS + ((wn * 32 + (l & 15)) << 7);

    f32x4 acc[8][4] = {};
    half8 af[4][2], bf0[2][2], bf1[2][2];

    const int nk = ksub >> 6;

    STAGEA(0, 0, 0); STAGEB(0, 0, 0); STAGEB(1, 0, 0); STAGEA(1, 0, 0);
    STAGEA(0, 1, 1); STAGEB(0, 1, 1); STAGEB(1, 1, 1); STAGEA(1, 1, 1);

    for (int kt = 0; kt < nk; ++kt) {
        const int p = kt & 1;
        const int ks = kt + 2;
        const bool hs = ks < nk;
        const char* pA = basePA + p * 32768;
        const char* pB = basePB + p * 32768;

        if (kt == nk - 1) VM0(); else VM8();
        BAR();

        READA(pA, 0); READB(pB, bf0, 0);
        LGKM8();
        BAR(); LGKM0();
        PRIO1(); MFMAB(0, 0, bf0); PRIO0(); BAR();

        READB(pB, bf1, 1);
        if (hs) { STAGEA(0, ks, p); STAGEB(0, ks, p); }
        BAR(); LGKM0();
        PRIO1(); MFMAB(0, 1, bf1); PRIO0(); BAR();

        READA(pA, 1);
        if (hs) STAGEB(1, ks, p);
        BAR(); LGKM0();
        PRIO1(); MFMAB(1, 1, bf1); PRIO0(); BAR();

        if (hs) STAGEA(1, ks, p);
        PRIO1(); MFMAB(1, 0, bf0); PRIO0(); BAR();
    }

    // block-cooperative f16 epilogue: [128][264] LDS restage -> 512B segments
    _Float16* eb = SM2;
    const int cr = (l >> 4) << 2;
    const int cc = l & 15;
#pragma unroll
    for (int h = 0; h < 2; ++h) {
        BAR();
#pragma unroll
        for (int mm = 0; mm < 4; ++mm) {
#pragma unroll
            for (int n = 0; n < 4; ++n) {
                const int lrow0 = wm * 64 + mm * 16 + cr;
                const int lcol = (n >> 1) * 128 + wn * 32 + (n & 1) * 16 + cc;
#pragma unroll
                for (int r = 0; r < 4; ++r)
                    eb[(lrow0 + r) * 264 + lcol] = (_Float16)acc[h * 4 + mm][n][r];
            }
        }
        LGKM0();
        BAR();
#pragma unroll
        for (int i = 0; i < 8; ++i) {
            const int lrow = w * 16 + i * 2 + (l >> 5);
            const half8 v = *(const half8*)(eb + lrow * 264 + (l & 31) * 8);
            const size_t row = m0 + (size_t)h * 128 + lrow;
            const size_t col = n0 + (l & 31) * 8;
            __builtin_nontemporal_store(v,
                (half8*)(C + coff + (long long)row * ldc + col));
        }
        LGKM0();
    }
}

// ============================== gemm128: fp32-out, col-bias (out-GEMM) ====
// 128x128 tile, BK=64, 4 waves, 64KB LDS -> 2 blocks/CU. Counted-vmcnt
// ledger: 8 loads/tile, VM8/tile. 2 phases/tile. LDS-staged epilogue.
#define STG128(SRC, LD, DST, KT) do { \
    const _Float16* _s = (SRC) + (size_t)(KT) * 64; \
    _Float16* _d = (DST) + 8 * w * 64; \
    gload_lds16(_s, _d); \
    gload_lds16(_s + (size_t)32 * (LD), _d + 2048); \
    gload_lds16(_s + (size_t)64 * (LD), _d + 4096); \
    gload_lds16(_s + (size_t)96 * (LD), _d + 6144); \
} while (0)

__global__ __launch_bounds__(256, 2)
void gemm128(const _Float16* __restrict__ A, const _Float16* __restrict__ B,
             float* __restrict__ C, const float* __restrict__ bias,
             int lda, int ldb, int ldc, int ksub,
             int ntx, int cpx) {
    __shared__ _Float16 SM[32768];   // As 2x8192 B, Bs 2x8192 B (64KB total)
    const int t = threadIdx.x;
    const int l = t & 63;
    const int w = t >> 6;
    const int wm = w >> 1, wn = w & 1;

    const int hb = blockIdx.x;
    const int lg = (hb & 7) * cpx + (hb >> 3);
    const int by = lg / ntx;
    const int bx = lg - by * ntx;
    const size_t m0 = (size_t)by * 128;
    const size_t n0 = (size_t)bx * 128;

    const int colsw = 8 * ((l & 7) ^ (l >> 3));
    const _Float16* srcA = A + (m0 + 8 * w + (l >> 3)) * (size_t)lda + colsw;
    const _Float16* srcB = B + (n0 + 8 * w + (l >> 3)) * (size_t)ldb + colsw;

    const int cx0 = (((l >> 4) << 4)) ^ ((l & 7) << 4);
    const int cx1 = (64 + ((l >> 4) << 4)) ^ ((l & 7) << 4);
    const char* basePA = (const char*)SM + ((wm * 64 + (l & 15)) << 7);
    const char* basePB = (const char*)SM + 32768 + ((wn * 64 + (l & 15)) << 7);

    f32x4 acc[4][4] = {};
    half8 af[4][2], bf[4][2];

    const int nk = ksub >> 6;   // 16 for K=1024

    STG128(srcA, lda, SM + 0, 0);        STG128(srcB, ldb, SM + 16384, 0);
    STG128(srcA, lda, SM + 8192, 1);     STG128(srcB, ldb, SM + 24576, 1);

    for (int kt = 0; kt < nk; ++kt) {
        const int p = kt & 1;
        const int ks = kt + 2;
        const bool hs = ks < nk;
        const char* pA = basePA + p * 16384;
        const char* pB = basePB + p * 16384;

        if (kt == nk - 1) VM0(); else VM8();
        BAR();

        // Ph1: read all fragments; MFMA k-slice 0
#pragma unroll
        for (int fm = 0; fm < 4; ++fm) {
            af[fm][0] = *(const half8*)(pA + ((fm * 16) << 7) + cx0);
            af[fm][1] = *(const half8*)(pA + ((fm * 16) << 7) + cx1);
        }
#pragma unroll
        for (int fn = 0; fn < 4; ++fn) {
            bf[fn][0] = *(const half8*)(pB + ((fn * 16) << 7) + cx0);
            bf[fn][1] = *(const half8*)(pB + ((fn * 16) << 7) + cx1);
        }
        LGKM0();
        PRIO1();
#pragma unroll
        for (int fm = 0; fm < 4; ++fm)
#pragma unroll
            for (int fn = 0; fn < 4; ++fn)
                acc[fm][fn] = __builtin_amdgcn_mfma_f32_16x16x32_f16(af[fm][0], bf[fn][0], acc[fm][fn], 0, 0, 0);
        PRIO0();
        BAR();

        // Ph2: stage tile kt+2 into buf p; MFMA k-slice 1
        if (hs) {
            STG128(srcA, lda, SM + p * 8192, ks);
            STG128(srcB, ldb, SM + 16384 + p * 8192, ks);
        }
        PRIO1();
#pragma unroll
        for (int fm = 0; fm < 4; ++fm)
#pragma unroll
            for (int fn = 0; fn < 4; ++fn)
                acc[fm][fn] = __builtin_amdgcn_mfma_f32_16x16x32_f16(af[fm][1], bf[fn][1], acc[fm][fn], 0, 0, 0);
        PRIO0();
        BAR();
    }

    // epilogue: per-wave private 16KB LDS; 2 chunks of 32 rows x 64 cols f32
    float* lw = (float*)((char*)SM + w * 16384);
    const int cr = (l >> 4) << 2;
    const int cc = l & 15;
    float bb4[4];
#pragma unroll
    for (int fn = 0; fn < 4; ++fn)
        bb4[fn] = bias[n0 + wn * 64 + fn * 16 + cc];
#pragma unroll
    for (int h = 0; h < 2; ++h) {
#pragma unroll
        for (int mm2 = 0; mm2 < 2; ++mm2) {
            const int mm = h * 2 + mm2;
#pragma unroll
            for (int fn = 0; fn < 4; ++fn) {
                const int lcol = fn * 16 + cc;
                const int lrow = mm2 * 16 + cr;
#pragma unroll
                for (int r = 0; r < 4; ++r)
                    lw[(lrow + r) * 68 + lcol] = acc[mm][fn][r] + bb4[fn];
            }
        }
        LGKM0();
        const size_t grow0 = m0 + (size_t)wm * 64 + h * 32;
#pragma unroll
        for (int i = 0; i < 8; ++i) {
            const int lrow = i * 4 + (l >> 4);
            const int lcol = (l & 15) * 4;
            const f32x4 v = *(const f32x4*)(lw + lrow * 68 + lcol);
            __builtin_nontemporal_store(v,
                (f32x4*)(C + (size_t)(grow0 + lrow) * ldc + n0 + wn * 64 + lcol));
        }
        LGKM0();
    }
}

// ------------------------------------------------- 128^2 engine (small GEMMs)
__global__ __launch_bounds__(256, 2)
void gemm_abt(const _Float16* __restrict__ A, const _Float16* __restrict__ B,
              float* __restrict__ C, int lda, int ldb, int ldc, int ksub,
              long long mn) {
    const int t = threadIdx.x;
    const int lane = t & 63;
    const int wave = t >> 6;
    const int wr = (wave >> 1) * 64;
    const int wc = (wave & 1) * 64;
    const size_t m0 = (size_t)blockIdx.y * 128;
    const size_t n0 = (size_t)blockIdx.x * 128;
    const size_t k0 = (size_t)blockIdx.z * (size_t)ksub;
    const long long coff = (long long)blockIdx.z * mn;

    __shared__ _Float16 As[128 * 32];
    __shared__ _Float16 Bs[128 * 32];

    f32x4 acc[4][4] = {};

    const _Float16* a0 = A + (m0 + (size_t)(t >> 2)) * (size_t)lda + k0 + (t & 3) * 8;
    const _Float16* a1 = a0 + (size_t)64 * lda;
    const _Float16* b0 = B + (n0 + (size_t)(t >> 2)) * (size_t)ldb + k0 + (t & 3) * 8;
    const _Float16* b1 = b0 + (size_t)64 * ldb;
    _Float16* AsW0 = As + wave * 512;
    _Float16* AsW1 = As + 2048 + wave * 512;
    _Float16* BsW0 = Bs + wave * 512;
    _Float16* BsW1 = Bs + 2048 + wave * 512;

    const int nk = ksub >> 5;
    for (int kt = 0; kt < nk; ++kt) {
        __syncthreads();
        gload_lds16(a0, AsW0);
        gload_lds16(a1, AsW1);
        gload_lds16(b0, BsW0);
        gload_lds16(b1, BsW1);
        a0 += 32; a1 += 32; b0 += 32; b1 += 32;
        __syncthreads();

        half8 af[4], bf[4];
#pragma unroll
        for (int i = 0; i < 4; ++i)
            af[i] = *(const half8*)(As + (wr + i * 16 + (lane & 15)) * 32 + (lane >> 4) * 8);
#pragma unroll
        for (int i = 0; i < 4; ++i)
            bf[i] = *(const half8*)(Bs + (wc + i * 16 + (lane & 15)) * 32 + (lane >> 4) * 8);
#pragma unroll
        for (int i = 0; i < 4; ++i)
#pragma unroll
            for (int j = 0; j < 4; ++j)
                acc[i][j] = __builtin_amdgcn_mfma_f32_16x16x32_f16(af[i], bf[j], acc[i][j], 0, 0, 0);
    }

    const int cr = (lane >> 4) * 4;
    const int cc = lane & 15;
#pragma unroll
    for (int i = 0; i < 4; ++i) {
#pragma unroll
        for (int j = 0; j < 4; ++j) {
            const size_t row0 = m0 + wr + i * 16 + cr;
            const size_t col = n0 + wc + j * 16 + cc;
#pragma unroll
            for (int r = 0; r < 4; ++r)
                C[coff + (long long)(row0 + r) * ldc + col] = acc[i][j][r];
        }
    }
}

// ------------------------------------------------------------- prep kernels
template <int WRITE_ROW, int COLSUM>
__global__ __launch_bounds__(256)
void cast_transpose(const float* __restrict__ in, _Float16* __restrict__ outRow,
                    _Float16* __restrict__ outT, float* __restrict__ msum, int ldT) {
    __shared__ _Float16 tile[64][66];
    __shared__ float red[16][16][4];
    const int t = threadIdx.x;
    const int c0 = blockIdx.x * 64;
    const int r0 = blockIdx.y * 64;
    const int cg = t & 15;
    const int rb = t >> 4;
    f32x4 csum = {};
#pragma unroll
    for (int it = 0; it < 4; ++it) {
        const int rr = rb + it * 16;
        f32x4 v = *(const f32x4*)(in + (size_t)(r0 + rr) * 1024 + c0 + cg * 4);
        if (COLSUM) { csum[0] += v[0]; csum[1] += v[1]; csum[2] += v[2]; csum[3] += v[3]; }
        _Float16 h0 = (_Float16)v[0], h1 = (_Float16)v[1];
        _Float16 h2 = (_Float16)v[2], h3 = (_Float16)v[3];
        tile[rr][cg * 4 + 0] = h0; tile[rr][cg * 4 + 1] = h1;
        tile[rr][cg * 4 + 2] = h2; tile[rr][cg * 4 + 3] = h3;
        if (WRITE_ROW) {
            half4 h = {h0, h1, h2, h3};
            *(half4*)(outRow + (size_t)(r0 + rr) * 1024 + c0 + cg * 4) = h;
        }
    }
    if (COLSUM) {
        red[rb][cg][0] = csum[0]; red[rb][cg][1] = csum[1];
        red[rb][cg][2] = csum[2]; red[rb][cg][3] = csum[3];
    }
    __syncthreads();
    if (COLSUM && t < 64) {
        float s = 0.f;
#pragma unroll
        for (int k = 0; k < 16; ++k) s += red[k][t >> 2][t & 3];
        atomicAdd(msum + c0 + t, s);
    }
    const int i = t >> 2, ch = (t & 3) * 16;
    half8 h0v, h1v;
#pragma unroll
    for (int j = 0; j < 8; ++j) h0v[j] = tile[ch + j][i];
#pragma unroll
    for (int j = 0; j < 8; ++j) h1v[j] = tile[ch + 8 + j][i];
    *(half8*)(outT + (size_t)(c0 + i) * ldT + r0 + ch) = h0v;
    *(half8*)(outT + (size_t)(c0 + i) * ldT + r0 + ch + 8) = h1v;
}

// Fused weight prep: blocks [0,512) Wq cast + dot(m)->u2; [512,1024) Wk
// cast + dot(m)->w; [1024,1280) Wv transpose-cast.
__global__ __launch_bounds__(256)
void prep_w(const float* __restrict__ Wq, const float* __restrict__ Wk,
            const float* __restrict__ Wv, const float* __restrict__ bq,
            const float* __restrict__ m,
            _Float16* __restrict__ wq16, _Float16* __restrict__ wk16,
            _Float16* __restrict__ wvT16,
            float* __restrict__ u2, float* __restrict__ w) {
    __shared__ _Float16 tile[64][66];
    __shared__ float wred[4];
    const int b = blockIdx.x;
    const int t = threadIdx.x;

    if (b < 1024) {
        const bool isQ = b < 512;
        const int bb = isQ ? b : b - 512;
        const float* W = isQ ? Wq : Wk;
        _Float16* o = isQ ? wq16 : wk16;
        const size_t base = (size_t)bb * 2048 + (size_t)t * 8;
        const f32x4* p = (const f32x4*)(W + base);
        f32x4 x0 = p[0], x1 = p[1];
        half8 h;
        h[0] = (_Float16)x0[0]; h[1] = (_Float16)x0[1];
        h[2] = (_Float16)x0[2]; h[3] = (_Float16)x0[3];
        h[4] = (_Float16)x1[0]; h[5] = (_Float16)x1[1];
        h[6] = (_Float16)x1[2]; h[7] = (_Float16)x1[3];
        ((half8*)o)[bb * 256 + t] = h;
        const int col = (t * 8) & 1023;
        f32x4 m0 = *(const f32x4*)(m + col);
        f32x4 m1 = *(const f32x4*)(m + col + 4);
        float s = x0[0] * m0[0] + x0[1] * m0[1] + x0[2] * m0[2] + x0[3] * m0[3]
                + x1[0] * m1[0] + x1[1] * m1[1] + x1[2] * m1[2] + x1[3] * m1[3];
        for (int o2 = 32; o2; o2 >>= 1) s += __shfl_xor(s, o2);
        if ((t & 63) == 0) wred[t >> 6] = s;
        __syncthreads();
        if (t == 0) {
            const int rA = 2 * bb, rB = 2 * bb + 1;
            const float vA = wred[0] + wred[1];
            const float vB = wred[2] + wred[3];
            if (isQ) {
                u2[rA] = vA + 16384.0f * bq[rA];
                u2[rB] = vB + 16384.0f * bq[rB];
            } else {
                w[rA] = vA;
                w[rB] = vB;
            }
        }
        return;
    }

    const int bb = b - 1024;
    const int c0 = (bb & 15) * 64;
    const int r0 = (bb >> 4) * 64;
    const int cg = t & 15;
    const int rb = t >> 4;
#pragma unroll
    for (int it = 0; it < 4; ++it) {
        const int rr = rb + it * 16;
        f32x4 v = *(const f32x4*)(Wv + (size_t)(r0 + rr) * 1024 + c0 + cg * 4);
        tile[rr][cg * 4 + 0] = (_Float16)v[0];
        tile[rr][cg * 4 + 1] = (_Float16)v[1];
        tile[rr][cg * 4 + 2] = (_Float16)v[2];
        tile[rr][cg * 4 + 3] = (_Float16)v[3];
    }
    __syncthreads();
    const int i = t >> 2, ch = (t & 3) * 16;
    half8 h0v, h1v;
#pragma unroll
    for (int j = 0; j < 8; ++j) h0v[j] = tile[ch + j][i];
#pragma unroll
    for (int j = 0; j < 8; ++j) h1v[j] = tile[ch + 8 + j][i];
    *(half8*)(wvT16 + (size_t)(c0 + i) * 1024 + r0 + ch) = h0v;
    *(half8*)(wvT16 + (size_t)(c0 + i) * 1024 + r0 + ch + 8) = h1v;
}

__global__ void zero_vec(float* __restrict__ p, int n) {
    int i = blockIdx.x * 256 + threadIdx.x;
    if (i < n) p[i] = 0.f;
}

__global__ __launch_bounds__(256)
void reduce_g(const _Float16* __restrict__ part, _Float16* __restrict__ G16) {
    const size_t off = ((size_t)blockIdx.x * 256 + threadIdx.x) * 8;
    float s[8] = {};
    for (int z = 0; z < 16; ++z) {
        half8 v = *(const half8*)(part + (size_t)z * 1048576 + off);
#pragma unroll
        for (int j = 0; j < 8; ++j) s[j] += (float)v[j];
    }
    half8 o;
#pragma unroll
    for (int j = 0; j < 8; ++j) o[j] = (_Float16)s[j];
    *(half8*)(G16 + off) = o;
}

__global__ __launch_bounds__(256)
void reduce_cast(const float* __restrict__ part, _Float16* __restrict__ outh,
                 int nz, float scale) {
    const int idx = (blockIdx.x * 256 + threadIdx.x) * 4;
    f32x4 s = {};
    for (int z = 0; z < nz; ++z) {
        f32x4 v = *(const f32x4*)(part + (size_t)z * 1048576 + idx);
        s[0] += v[0]; s[1] += v[1]; s[2] += v[2]; s[3] += v[3];
    }
    half4 h;
    h[0] = (_Float16)(s[0] * scale); h[1] = (_Float16)(s[1] * scale);
    h[2] = (_Float16)(s[2] * scale); h[3] = (_Float16)(s[3] * scale);
    *(half4*)(outh + idx) = h;
}

// reduce 4 split-K fp32 slices + rank-1 terms + 1/32 scale + row-softmax
__global__ __launch_bounds__(256)
void softmax_rows(const float* __restrict__ part, const float* __restrict__ u2,
                  const float* __restrict__ bq, const float* __restrict__ bk,
                  const float* __restrict__ w,
                  float* __restrict__ P, _Float16* __restrict__ PT) {
    const int a = blockIdx.x;
    const int t = threadIdx.x;
    __shared__ float red[8];
    const size_t off = (size_t)a * 1024 + t * 4;
    f32x4 s = {};
#pragma unroll
    for (int z = 0; z < 4; ++z) {
        f32x4 v = *(const f32x4*)(part + (size_t)z * 1048576 + off);
        s[0] += v[0]; s[1] += v[1]; s[2] += v[2]; s[3] += v[3];
    }
    const float ru = u2[a], rb = bq[a];
    f32x4 bk4 = *(const f32x4*)(bk + t * 4);
    f32x4 w4 = *(const f32x4*)(w + t * 4);
#pragma unroll
    for (int j = 0; j < 4; ++j) s[j] = (s[j] + ru * bk4[j] + rb * w4[j]) * 0.03125f;

    float m = fmaxf(fmaxf(s[0], s[1]), fmaxf(s[2], s[3]));
    for (int o = 32; o; o >>= 1) m = fmaxf(m, __shfl_xor(m, o));
    if ((t & 63) == 0) red[t >> 6] = m;
    __syncthreads();
    m = fmaxf(fmaxf(red[0], red[1]), fmaxf(red[2], red[3]));

    float e0 = expf(s[0] - m), e1 = expf(s[1] - m);
    float e2 = expf(s[2] - m), e3 = expf(s[3] - m);
    float sum = e0 + e1 + e2 + e3;
    for (int o = 32; o; o >>= 1) sum += __shfl_xor(sum, o);
    if ((t & 63) == 0) red[4 + (t >> 6)] = sum;
    __syncthreads();
    sum = red[4] + red[5] + red[6] + red[7];
    const float inv = 1.0f / sum;

    f32x4 o4 = {e0 * inv, e1 * inv, e2 * inv, e3 * inv};
    *(f32x4*)(P + off) = o4;
    const int b = t * 4;
    PT[(size_t)(b + 0) * 1024 + a] = (_Float16)o4[0];
    PT[(size_t)(b + 1) * 1024 + a] = (_Float16)o4[1];
    PT[(size_t)(b + 2) * 1024 + a] = (_Float16)o4[2];
    PT[(size_t)(b + 3) * 1024 + a] = (_Float16)o4[3];
}

__global__ __launch_bounds__(256)
void attn_bv(const float* __restrict__ attn, const float* __restrict__ bv,
             float* __restrict__ c) {
    const int j = blockIdx.x * 256 + threadIdx.x;
    const int a0 = blockIdx.y * 64;
    float s = 0.f;
#pragma unroll 4
    for (int k = 0; k < 64; ++k) {
        const int a = a0 + k;
        s += attn[(size_t)a * 1024 + j] * bv[a];
    }
    atomicAdd(c + j, s);
}

extern "C" void kernel_launch(void* const* d_in, const int* in_sizes, int n_in,
                              void* d_out, int out_size, void* d_ws, size_t ws_size,
                              hipStream_t stream) {
    const float* x  = (const float*)d_in[0];
    const float* Wq = (const float*)d_in[1];
    const float* bq = (const float*)d_in[2];
    const float* Wk = (const float*)d_in[3];
    const float* bk = (const float*)d_in[4];
    const float* Wv = (const float*)d_in[5];
    const float* bv = (const float*)d_in[6];
    float* out  = (float*)d_out;                   // [S,D] fp32
    float* attn = out + (size_t)S_ * D_;           // [D,D] fp32

    char* ws = (char*)d_ws;
    float*    part  = (float*)ws;                          // 32MB, reused
    _Float16* partH = (_Float16*)ws;                       // G f16 partials
    _Float16* x16   = (_Float16*)(ws + 33554432);          // [S,D]   33.5MB
    _Float16* xT16  = (_Float16*)(ws + 67108864);          // [D,S]   33.5MB
    _Float16* wq16  = (_Float16*)(ws + 100663296);         // [D,D]   2MB
    _Float16* wk16  = (_Float16*)(ws + 102760448);
    _Float16* wvT16 = (_Float16*)(ws + 104857600);
    _Float16* G16   = (_Float16*)(ws + 106954752);
    _Float16* U16   = (_Float16*)(ws + 109051904);
    _Float16* PT    = (_Float16*)(ws + 111149056);
    _Float16* MT16  = (_Float16*)(ws + 113246208);
    float*    mvec  = (float*)(ws + 115343360);            // m, u2, w, c
    float*    u2    = mvec + 1024;
    float*    wv    = u2 + 1024;
    float*    cvec  = wv + 1024;

    zero_vec<<<16, 256, 0, stream>>>(mvec, 4096);
    cast_transpose<1, 1><<<dim3(16, 256), 256, 0, stream>>>(x, x16, xT16, mvec, S_);
    prep_w<<<1280, 256, 0, stream>>>(Wq, Wk, Wv, bq, mvec,
                                     wq16, wk16, wvT16, u2, wv);

    // G = xT * xT^T  (M=N=1024, K=16384, split-K 16, f16 partials)
    gemm256<<<256, 512, 0, stream>>>(xT16, xT16, partH,
                                     16384, 16384, 1024, 1024, 1048576LL,
                                     4, 16, 32);
    reduce_g<<<512, 256, 0, stream>>>(partH, G16);
    // U = Wq * G  (split-K4, fp32 partials)
    gemm_abt<<<dim3(8, 8, 4), 256, 0, stream>>>(wq16, G16, part,
                                                1024, 1024, 1024, 256, 1048576);
    reduce_cast<<<1024, 256, 0, stream>>>(part, U16, 4, 1.0f);
    // scores partials = U * Wk^T (split-K4; rank-1 + scale fused in softmax)
    gemm_abt<<<dim3(8, 8, 4), 256, 0, stream>>>(U16, wk16, part,
                                                1024, 1024, 1024, 256, 1048576);
    softmax_rows<<<1024, 256, 0, stream>>>(part, u2, bq, bk, wv, attn, PT);
    attn_bv<<<dim3(4, 16), 256, 0, stream>>>(attn, bv, cvec);
    // MT[j,i] = sum_a attn[a,j] Wv[a,i]  (split-K4)
    gemm_abt<<<dim3(8, 8, 4), 256, 0, stream>>>(PT, wvT16, part,
                                                1024, 1024, 1024, 256, 1048576);
    reduce_cast<<<1024, 256, 0, stream>>>(part, MT16, 4, 1.0f);
    // out = x16 * MT^T + cvec  (M=16384, N=1024, K=1024; 1024 blocks, 2/CU)
    gemm128<<<1024, 256, 0, stream>>>(x16, MT16, out, cvec,
                                      1024, 1024, 1024, 1024, 8, 128);
}

// Round 11
// 177.211 us; speedup vs baseline: 1.0580x; 1.0326x over previous
//
#include <hip/hip_runtime.h>
#include <hip/hip_bf16.h>
#include <stdint.h>

// BertAttention (feature-axis attention), algebraically restructured:
//   G = x^T x  [D,D];  m = colsum(x);  u2 = Wq m + S*bq;  w = Wk m
//   scores = (Wq G Wk^T + u2 bk^T + bq w^T)/sqrt(D); attn = softmax(scores)
//   out = x (Wv^T attn) + 1 (bv^T attn)
// G: 256x256 8-wave counted-vmcnt engine + block-cooperative f16 epilogue.
// out: 128x128 gemm128 (2 blk/CU). Small 1024^3 GEMMs: gemm128-style
// split-K4 counted-vmcnt engine (upgraded from naive 2-barrier loop).

#define S_ 16384
#define D_ 1024

typedef _Float16 half8 __attribute__((ext_vector_type(8)));
typedef _Float16 half4 __attribute__((ext_vector_type(4)));
typedef float f32x4 __attribute__((ext_vector_type(4)));

__device__ __forceinline__ void gload_lds16(const _Float16* g, _Float16* l) {
    __builtin_amdgcn_global_load_lds(
        (const __attribute__((address_space(1))) void*)g,
        (__attribute__((address_space(3))) void*)l, 16, 0, 0);
}

#define VM8() do { asm volatile("s_waitcnt vmcnt(8)" ::: "memory"); __builtin_amdgcn_sched_barrier(0); } while (0)
#define VM0() do { asm volatile("s_waitcnt vmcnt(0)" ::: "memory"); __builtin_amdgcn_sched_barrier(0); } while (0)
#define BAR() __builtin_amdgcn_s_barrier()
#define LGKM0() do { asm volatile("s_waitcnt lgkmcnt(0)" ::: "memory"); __builtin_amdgcn_sched_barrier(0); } while (0)
#define LGKM8() do { asm volatile("s_waitcnt lgkmcnt(8)" ::: "memory"); __builtin_amdgcn_sched_barrier(0); } while (0)
#define PRIO1() __builtin_amdgcn_s_setprio(1)
#define PRIO0() __builtin_amdgcn_s_setprio(0)

// ====================================================== gemm256 (G only)
#define STAGEA(H, KT, NX) do { \
    const _Float16* _s = srcA + (size_t)((H) * 128) * lda + (size_t)(KT) * 64; \
    _Float16* _d = AsS + (NX) * 16384 + ((H) * 128 + 8 * w) * 64; \
    gload_lds16(_s, _d); \
    gload_lds16(_s + (size_t)64 * lda, _d + 4096); \
} while (0)

#define STAGEB(H, KT, NX) do { \
    const _Float16* _s = srcB + (size_t)((H) * 128) * ldb + (size_t)(KT) * 64; \
    _Float16* _d = BsS + (NX) * 16384 + ((H) * 128 + 8 * w) * 64; \
    gload_lds16(_s, _d); \
    gload_lds16(_s + (size_t)64 * ldb, _d + 4096); \
} while (0)

#define READA(PA, QA) do { _Pragma("unroll") \
    for (int fm = 0; fm < 4; ++fm) { \
        af[fm][0] = *(const half8*)((PA) + (((QA) * 128 + fm * 16) << 7) + cx0); \
        af[fm][1] = *(const half8*)((PA) + (((QA) * 128 + fm * 16) << 7) + cx1); } \
} while (0)

#define READB(PB, BF, QB) do { _Pragma("unroll") \
    for (int fn = 0; fn < 2; ++fn) { \
        BF[fn][0] = *(const half8*)((PB) + (((QB) * 128 + fn * 16) << 7) + cx0); \
        BF[fn][1] = *(const half8*)((PB) + (((QB) * 128 + fn * 16) << 7) + cx1); } \
} while (0)

#define MFMAB(QA, QB, BF) do { _Pragma("unroll") \
    for (int fm = 0; fm < 4; ++fm) { _Pragma("unroll") \
        for (int fn = 0; fn < 2; ++fn) { \
            f32x4 _c = acc[(QA) * 4 + fm][(QB) * 2 + fn]; \
            _c = __builtin_amdgcn_mfma_f32_16x16x32_f16(af[fm][0], BF[fn][0], _c, 0, 0, 0); \
            _c = __builtin_amdgcn_mfma_f32_16x16x32_f16(af[fm][1], BF[fn][1], _c, 0, 0, 0); \
            acc[(QA) * 4 + fm][(QB) * 2 + fn] = _c; } } \
} while (0)

// f16-out, split-K partials. Used for G = xT xT^T.
__global__ __launch_bounds__(512, 2)
void gemm256(const _Float16* __restrict__ A, const _Float16* __restrict__ B,
             _Float16* __restrict__ C,
             int lda, int ldb, int ldc, int ksub, long long mn,
             int ntx, int ntxy, int cpx) {
    __shared__ _Float16 SM2[65536];   // 128KB: As 2x16384, Bs 2x16384
    _Float16* AsS = SM2;
    _Float16* BsS = SM2 + 32768;
    const int t = threadIdx.x;
    const int l = t & 63;
    const int w = t >> 6;
    const int wm = w >> 2, wn = w & 3;

    const int hb = blockIdx.x;
    const int lg = (hb & 7) * cpx + (hb >> 3);
    const int bz = lg / ntxy;
    const int rem = lg - bz * ntxy;
    const int by = rem / ntx;
    const int bx = rem - by * ntx;
    const size_t m0 = (size_t)by * 256;
    const size_t n0 = (size_t)bx * 256;
    const size_t k0 = (size_t)bz * (size_t)ksub;
    const long long coff = (long long)bz * mn;

    const int colsw = 8 * ((l & 7) ^ (l >> 3));
    const _Float16* srcA = A + (m0 + 8 * w + (l >> 3)) * (size_t)lda + k0 + colsw;
    const _Float16* srcB = B + (n0 + 8 * w + (l >> 3)) * (size_t)ldb + k0 + colsw;

    const int cx0 = (((l >> 4) << 4)) ^ ((l & 7) << 4);
    const int cx1 = (64 + ((l >> 4) << 4)) ^ ((l & 7) << 4);
    const char* basePA = (const char*)AsS + ((wm * 64 + (l & 15)) << 7);
    const char* basePB = (const char*)BsS + ((wn * 32 + (l & 15)) << 7);

    f32x4 acc[8][4] = {};
    half8 af[4][2], bf0[2][2], bf1[2][2];

    const int nk = ksub >> 6;

    STAGEA(0, 0, 0); STAGEB(0, 0, 0); STAGEB(1, 0, 0); STAGEA(1, 0, 0);
    STAGEA(0, 1, 1); STAGEB(0, 1, 1); STAGEB(1, 1, 1); STAGEA(1, 1, 1);

    for (int kt = 0; kt < nk; ++kt) {
        const int p = kt & 1;
        const int ks = kt + 2;
        const bool hs = ks < nk;
        const char* pA = basePA + p * 32768;
        const char* pB = basePB + p * 32768;

        if (kt == nk - 1) VM0(); else VM8();
        BAR();

        READA(pA, 0); READB(pB, bf0, 0);
        LGKM8();
        BAR(); LGKM0();
        PRIO1(); MFMAB(0, 0, bf0); PRIO0(); BAR();

        READB(pB, bf1, 1);
        if (hs) { STAGEA(0, ks, p); STAGEB(0, ks, p); }
        BAR(); LGKM0();
        PRIO1(); MFMAB(0, 1, bf1); PRIO0(); BAR();

        READA(pA, 1);
        if (hs) STAGEB(1, ks, p);
        BAR(); LGKM0();
        PRIO1(); MFMAB(1, 1, bf1); PRIO0(); BAR();

        if (hs) STAGEA(1, ks, p);
        PRIO1(); MFMAB(1, 0, bf0); PRIO0(); BAR();
    }

    // block-cooperative f16 epilogue: [128][264] LDS restage -> 512B segments
    _Float16* eb = SM2;
    const int cr = (l >> 4) << 2;
    const int cc = l & 15;
#pragma unroll
    for (int h = 0; h < 2; ++h) {
        BAR();
#pragma unroll
        for (int mm = 0; mm < 4; ++mm) {
#pragma unroll
            for (int n = 0; n < 4; ++n) {
                const int lrow0 = wm * 64 + mm * 16 + cr;
                const int lcol = (n >> 1) * 128 + wn * 32 + (n & 1) * 16 + cc;
#pragma unroll
                for (int r = 0; r < 4; ++r)
                    eb[(lrow0 + r) * 264 + lcol] = (_Float16)acc[h * 4 + mm][n][r];
            }
        }
        LGKM0();
        BAR();
#pragma unroll
        for (int i = 0; i < 8; ++i) {
            const int lrow = w * 16 + i * 2 + (l >> 5);
            const half8 v = *(const half8*)(eb + lrow * 264 + (l & 31) * 8);
            const size_t row = m0 + (size_t)h * 128 + lrow;
            const size_t col = n0 + (l & 31) * 8;
            __builtin_nontemporal_store(v,
                (half8*)(C + coff + (long long)row * ldc + col));
        }
        LGKM0();
    }
}

// ============================== gemm128: fp32-out, col-bias (out-GEMM) ====
#define STG128(SRC, LD, DST, KT) do { \
    const _Float16* _s = (SRC) + (size_t)(KT) * 64; \
    _Float16* _d = (DST) + 8 * w * 64; \
    gload_lds16(_s, _d); \
    gload_lds16(_s + (size_t)32 * (LD), _d + 2048); \
    gload_lds16(_s + (size_t)64 * (LD), _d + 4096); \
    gload_lds16(_s + (size_t)96 * (LD), _d + 6144); \
} while (0)

__global__ __launch_bounds__(256, 2)
void gemm128(const _Float16* __restrict__ A, const _Float16* __restrict__ B,
             float* __restrict__ C, const float* __restrict__ bias,
             int lda, int ldb, int ldc, int ksub,
             int ntx, int cpx) {
    __shared__ _Float16 SM[32768];
    const int t = threadIdx.x;
    const int l = t & 63;
    const int w = t >> 6;
    const int wm = w >> 1, wn = w & 1;

    const int hb = blockIdx.x;
    const int lg = (hb & 7) * cpx + (hb >> 3);
    const int by = lg / ntx;
    const int bx = lg - by * ntx;
    const size_t m0 = (size_t)by * 128;
    const size_t n0 = (size_t)bx * 128;

    const int colsw = 8 * ((l & 7) ^ (l >> 3));
    const _Float16* srcA = A + (m0 + 8 * w + (l >> 3)) * (size_t)lda + colsw;
    const _Float16* srcB = B + (n0 + 8 * w + (l >> 3)) * (size_t)ldb + colsw;

    const int cx0 = (((l >> 4) << 4)) ^ ((l & 7) << 4);
    const int cx1 = (64 + ((l >> 4) << 4)) ^ ((l & 7) << 4);
    const char* basePA = (const char*)SM + ((wm * 64 + (l & 15)) << 7);
    const char* basePB = (const char*)SM + 32768 + ((wn * 64 + (l & 15)) << 7);

    f32x4 acc[4][4] = {};
    half8 af[4][2], bf[4][2];

    const int nk = ksub >> 6;

    STG128(srcA, lda, SM + 0, 0);        STG128(srcB, ldb, SM + 16384, 0);
    STG128(srcA, lda, SM + 8192, 1);     STG128(srcB, ldb, SM + 24576, 1);

    for (int kt = 0; kt < nk; ++kt) {
        const int p = kt & 1;
        const int ks = kt + 2;
        const bool hs = ks < nk;
        const char* pA = basePA + p * 16384;
        const char* pB = basePB + p * 16384;

        if (kt == nk - 1) VM0(); else VM8();
        BAR();

#pragma unroll
        for (int fm = 0; fm < 4; ++fm) {
            af[fm][0] = *(const half8*)(pA + ((fm * 16) << 7) + cx0);
            af[fm][1] = *(const half8*)(pA + ((fm * 16) << 7) + cx1);
        }
#pragma unroll
        for (int fn = 0; fn < 4; ++fn) {
            bf[fn][0] = *(const half8*)(pB + ((fn * 16) << 7) + cx0);
            bf[fn][1] = *(const half8*)(pB + ((fn * 16) << 7) + cx1);
        }
        LGKM0();
        PRIO1();
#pragma unroll
        for (int fm = 0; fm < 4; ++fm)
#pragma unroll
            for (int fn = 0; fn < 4; ++fn)
                acc[fm][fn] = __builtin_amdgcn_mfma_f32_16x16x32_f16(af[fm][0], bf[fn][0], acc[fm][fn], 0, 0, 0);
        PRIO0();
        BAR();

        if (hs) {
            STG128(srcA, lda, SM + p * 8192, ks);
            STG128(srcB, ldb, SM + 16384 + p * 8192, ks);
        }
        PRIO1();
#pragma unroll
        for (int fm = 0; fm < 4; ++fm)
#pragma unroll
            for (int fn = 0; fn < 4; ++fn)
                acc[fm][fn] = __builtin_amdgcn_mfma_f32_16x16x32_f16(af[fm][1], bf[fn][1], acc[fm][fn], 0, 0, 0);
        PRIO0();
        BAR();
    }

    float* lw = (float*)((char*)SM + w * 16384);
    const int cr = (l >> 4) << 2;
    const int cc = l & 15;
    float bb4[4];
#pragma unroll
    for (int fn = 0; fn < 4; ++fn)
        bb4[fn] = bias[n0 + wn * 64 + fn * 16 + cc];
#pragma unroll
    for (int h = 0; h < 2; ++h) {
#pragma unroll
        for (int mm2 = 0; mm2 < 2; ++mm2) {
            const int mm = h * 2 + mm2;
#pragma unroll
            for (int fn = 0; fn < 4; ++fn) {
                const int lcol = fn * 16 + cc;
                const int lrow = mm2 * 16 + cr;
#pragma unroll
                for (int r = 0; r < 4; ++r)
                    lw[(lrow + r) * 68 + lcol] = acc[mm][fn][r] + bb4[fn];
            }
        }
        LGKM0();
        const size_t grow0 = m0 + (size_t)wm * 64 + h * 32;
#pragma unroll
        for (int i = 0; i < 8; ++i) {
            const int lrow = i * 4 + (l >> 4);
            const int lcol = (l & 15) * 4;
            const f32x4 v = *(const f32x4*)(lw + lrow * 68 + lcol);
            __builtin_nontemporal_store(v,
                (f32x4*)(C + (size_t)(grow0 + lrow) * ldc + n0 + wn * 64 + lcol));
        }
        LGKM0();
    }
}

// ======== gemm_s128: split-K small-GEMM engine (gemm128 structure) ========
// 128x128 tile, BK=64, 4 waves, counted-vmcnt VM8 ledger, XOR swizzle,
// LDS-staged epilogue with PLAIN fp32 partial stores (L2-resident).
__global__ __launch_bounds__(256, 2)
void gemm_s128(const _Float16* __restrict__ A, const _Float16* __restrict__ B,
               float* __restrict__ C, int lda, int ldb, int ldc, int ksub,
               long long mn) {
    __shared__ _Float16 SM[32768];
    const int t = threadIdx.x;
    const int l = t & 63;
    const int w = t >> 6;
    const int wm = w >> 1, wn = w & 1;

    const size_t m0 = (size_t)blockIdx.y * 128;
    const size_t n0 = (size_t)blockIdx.x * 128;
    const size_t k0 = (size_t)blockIdx.z * (size_t)ksub;
    const long long coff = (long long)blockIdx.z * mn;

    const int colsw = 8 * ((l & 7) ^ (l >> 3));
    const _Float16* srcA = A + (m0 + 8 * w + (l >> 3)) * (size_t)lda + k0 + colsw;
    const _Float16* srcB = B + (n0 + 8 * w + (l >> 3)) * (size_t)ldb + k0 + colsw;

    const int cx0 = (((l >> 4) << 4)) ^ ((l & 7) << 4);
    const int cx1 = (64 + ((l >> 4) << 4)) ^ ((l & 7) << 4);
    const char* basePA = (const char*)SM + ((wm * 64 + (l & 15)) << 7);
    const char* basePB = (const char*)SM + 32768 + ((wn * 64 + (l & 15)) << 7);

    f32x4 acc[4][4] = {};
    half8 af[4][2], bf[4][2];

    const int nk = ksub >> 6;   // 4 for ksub=256

    STG128(srcA, lda, SM + 0, 0);        STG128(srcB, ldb, SM + 16384, 0);
    STG128(srcA, lda, SM + 8192, 1);     STG128(srcB, ldb, SM + 24576, 1);

    for (int kt = 0; kt < nk; ++kt) {
        const int p = kt & 1;
        const int ks = kt + 2;
        const bool hs = ks < nk;
        const char* pA = basePA + p * 16384;
        const char* pB = basePB + p * 16384;

        if (kt == nk - 1) VM0(); else VM8();
        BAR();

#pragma unroll
        for (int fm = 0; fm < 4; ++fm) {
            af[fm][0] = *(const half8*)(pA + ((fm * 16) << 7) + cx0);
            af[fm][1] = *(const half8*)(pA + ((fm * 16) << 7) + cx1);
        }
#pragma unroll
        for (int fn = 0; fn < 4; ++fn) {
            bf[fn][0] = *(const half8*)(pB + ((fn * 16) << 7) + cx0);
            bf[fn][1] = *(const half8*)(pB + ((fn * 16) << 7) + cx1);
        }
        LGKM0();
        PRIO1();
#pragma unroll
        for (int fm = 0; fm < 4; ++fm)
#pragma unroll
            for (int fn = 0; fn < 4; ++fn)
                acc[fm][fn] = __builtin_amdgcn_mfma_f32_16x16x32_f16(af[fm][0], bf[fn][0], acc[fm][fn], 0, 0, 0);
        PRIO0();
        BAR();

        if (hs) {
            STG128(srcA, lda, SM + p * 8192, ks);
            STG128(srcB, ldb, SM + 16384 + p * 8192, ks);
        }
        PRIO1();
#pragma unroll
        for (int fm = 0; fm < 4; ++fm)
#pragma unroll
            for (int fn = 0; fn < 4; ++fn)
                acc[fm][fn] = __builtin_amdgcn_mfma_f32_16x16x32_f16(af[fm][1], bf[fn][1], acc[fm][fn], 0, 0, 0);
        PRIO0();
        BAR();
    }

    // LDS-staged epilogue, plain stores (partials are re-read -> keep in L2)
    float* lw = (float*)((char*)SM + w * 16384);
    const int cr = (l >> 4) << 2;
    const int cc = l & 15;
#pragma unroll
    for (int h = 0; h < 2; ++h) {
#pragma unroll
        for (int mm2 = 0; mm2 < 2; ++mm2) {
            const int mm = h * 2 + mm2;
#pragma unroll
            for (int fn = 0; fn < 4; ++fn) {
                const int lcol = fn * 16 + cc;
                const int lrow = mm2 * 16 + cr;
#pragma unroll
                for (int r = 0; r < 4; ++r)
                    lw[(lrow + r) * 68 + lcol] = acc[mm][fn][r];
            }
        }
        LGKM0();
        const size_t grow0 = m0 + (size_t)wm * 64 + h * 32;
#pragma unroll
        for (int i = 0; i < 8; ++i) {
            const int lrow = i * 4 + (l >> 4);
            const int lcol = (l & 15) * 4;
            const f32x4 v = *(const f32x4*)(lw + lrow * 68 + lcol);
            *(f32x4*)(C + coff + (long long)(grow0 + lrow) * ldc + n0 + wn * 64 + lcol) = v;
        }
        LGKM0();
    }
}

// ------------------------------------------------------------- prep kernels
template <int WRITE_ROW, int COLSUM>
__global__ __launch_bounds__(256)
void cast_transpose(const float* __restrict__ in, _Float16* __restrict__ outRow,
                    _Float16* __restrict__ outT, float* __restrict__ msum, int ldT) {
    __shared__ _Float16 tile[64][66];
    __shared__ float red[16][16][4];
    const int t = threadIdx.x;
    const int c0 = blockIdx.x * 64;
    const int r0 = blockIdx.y * 64;
    const int cg = t & 15;
    const int rb = t >> 4;
    f32x4 csum = {};
#pragma unroll
    for (int it = 0; it < 4; ++it) {
        const int rr = rb + it * 16;
        f32x4 v = *(const f32x4*)(in + (size_t)(r0 + rr) * 1024 + c0 + cg * 4);
        if (COLSUM) { csum[0] += v[0]; csum[1] += v[1]; csum[2] += v[2]; csum[3] += v[3]; }
        _Float16 h0 = (_Float16)v[0], h1 = (_Float16)v[1];
        _Float16 h2 = (_Float16)v[2], h3 = (_Float16)v[3];
        tile[rr][cg * 4 + 0] = h0; tile[rr][cg * 4 + 1] = h1;
        tile[rr][cg * 4 + 2] = h2; tile[rr][cg * 4 + 3] = h3;
        if (WRITE_ROW) {
            half4 h = {h0, h1, h2, h3};
            *(half4*)(outRow + (size_t)(r0 + rr) * 1024 + c0 + cg * 4) = h;
        }
    }
    if (COLSUM) {
        red[rb][cg][0] = csum[0]; red[rb][cg][1] = csum[1];
        red[rb][cg][2] = csum[2]; red[rb][cg][3] = csum[3];
    }
    __syncthreads();
    if (COLSUM && t < 64) {
        float s = 0.f;
#pragma unroll
        for (int k = 0; k < 16; ++k) s += red[k][t >> 2][t & 3];
        atomicAdd(msum + c0 + t, s);
    }
    const int i = t >> 2, ch = (t & 3) * 16;
    half8 h0v, h1v;
#pragma unroll
    for (int j = 0; j < 8; ++j) h0v[j] = tile[ch + j][i];
#pragma unroll
    for (int j = 0; j < 8; ++j) h1v[j] = tile[ch + 8 + j][i];
    *(half8*)(outT + (size_t)(c0 + i) * ldT + r0 + ch) = h0v;
    *(half8*)(outT + (size_t)(c0 + i) * ldT + r0 + ch + 8) = h1v;
}

// Fused weight prep: blocks [0,512) Wq cast + dot(m)->u2; [512,1024) Wk
// cast + dot(m)->w; [1024,1280) Wv transpose-cast.
__global__ __launch_bounds__(256)
void prep_w(const float* __restrict__ Wq, const float* __restrict__ Wk,
            const float* __restrict__ Wv, const float* __restrict__ bq,
            const float* __restrict__ m,
            _Float16* __restrict__ wq16, _Float16* __restrict__ wk16,
            _Float16* __restrict__ wvT16,
            float* __restrict__ u2, float* __restrict__ w) {
    __shared__ _Float16 tile[64][66];
    __shared__ float wred[4];
    const int b = blockIdx.x;
    const int t = threadIdx.x;

    if (b < 1024) {
        const bool isQ = b < 512;
        const int bb = isQ ? b : b - 512;
        const float* W = isQ ? Wq : Wk;
        _Float16* o = isQ ? wq16 : wk16;
        const size_t base = (size_t)bb * 2048 + (size_t)t * 8;
        const f32x4* p = (const f32x4*)(W + base);
        f32x4 x0 = p[0], x1 = p[1];
        half8 h;
        h[0] = (_Float16)x0[0]; h[1] = (_Float16)x0[1];
        h[2] = (_Float16)x0[2]; h[3] = (_Float16)x0[3];
        h[4] = (_Float16)x1[0]; h[5] = (_Float16)x1[1];
        h[6] = (_Float16)x1[2]; h[7] = (_Float16)x1[3];
        ((half8*)o)[bb * 256 + t] = h;
        const int col = (t * 8) & 1023;
        f32x4 m0 = *(const f32x4*)(m + col);
        f32x4 m1 = *(const f32x4*)(m + col + 4);
        float s = x0[0] * m0[0] + x0[1] * m0[1] + x0[2] * m0[2] + x0[3] * m0[3]
                + x1[0] * m1[0] + x1[1] * m1[1] + x1[2] * m1[2] + x1[3] * m1[3];
        for (int o2 = 32; o2; o2 >>= 1) s += __shfl_xor(s, o2);
        if ((t & 63) == 0) wred[t >> 6] = s;
        __syncthreads();
        if (t == 0) {
            const int rA = 2 * bb, rB = 2 * bb + 1;
            const float vA = wred[0] + wred[1];
            const float vB = wred[2] + wred[3];
            if (isQ) {
                u2[rA] = vA + 16384.0f * bq[rA];
                u2[rB] = vB + 16384.0f * bq[rB];
            } else {
                w[rA] = vA;
                w[rB] = vB;
            }
        }
        return;
    }

    const int bb = b - 1024;
    const int c0 = (bb & 15) * 64;
    const int r0 = (bb >> 4) * 64;
    const int cg = t & 15;
    const int rb = t >> 4;
#pragma unroll
    for (int it = 0; it < 4; ++it) {
        const int rr = rb + it * 16;
        f32x4 v = *(const f32x4*)(Wv + (size_t)(r0 + rr) * 1024 + c0 + cg * 4);
        tile[rr][cg * 4 + 0] = (_Float16)v[0];
        tile[rr][cg * 4 + 1] = (_Float16)v[1];
        tile[rr][cg * 4 + 2] = (_Float16)v[2];
        tile[rr][cg * 4 + 3] = (_Float16)v[3];
    }
    __syncthreads();
    const int i = t >> 2, ch = (t & 3) * 16;
    half8 h0v, h1v;
#pragma unroll
    for (int j = 0; j < 8; ++j) h0v[j] = tile[ch + j][i];
#pragma unroll
    for (int j = 0; j < 8; ++j) h1v[j] = tile[ch + 8 + j][i];
    *(half8*)(wvT16 + (size_t)(c0 + i) * 1024 + r0 + ch) = h0v;
    *(half8*)(wvT16 + (size_t)(c0 + i) * 1024 + r0 + ch + 8) = h1v;
}

__global__ void zero_vec(float* __restrict__ p, int n) {
    int i = blockIdx.x * 256 + threadIdx.x;
    if (i < n) p[i] = 0.f;
}

__global__ __launch_bounds__(256)
void reduce_g(const _Float16* __restrict__ part, _Float16* __restrict__ G16) {
    const size_t off = ((size_t)blockIdx.x * 256 + threadIdx.x) * 8;
    float s[8] = {};
    for (int z = 0; z < 16; ++z) {
        half8 v = *(const half8*)(part + (size_t)z * 1048576 + off);
#pragma unroll
        for (int j = 0; j < 8; ++j) s[j] += (float)v[j];
    }
    half8 o;
#pragma unroll
    for (int j = 0; j < 8; ++j) o[j] = (_Float16)s[j];
    *(half8*)(G16 + off) = o;
}

__global__ __launch_bounds__(256)
void reduce_cast(const float* __restrict__ part, _Float16* __restrict__ outh,
                 int nz, float scale) {
    const int idx = (blockIdx.x * 256 + threadIdx.x) * 4;
    f32x4 s = {};
    for (int z = 0; z < nz; ++z) {
        f32x4 v = *(const f32x4*)(part + (size_t)z * 1048576 + idx);
        s[0] += v[0]; s[1] += v[1]; s[2] += v[2]; s[3] += v[3];
    }
    half4 h;
    h[0] = (_Float16)(s[0] * scale); h[1] = (_Float16)(s[1] * scale);
    h[2] = (_Float16)(s[2] * scale); h[3] = (_Float16)(s[3] * scale);
    *(half4*)(outh + idx) = h;
}

// reduce 4 split-K fp32 slices + rank-1 terms + 1/32 scale + row-softmax
__global__ __launch_bounds__(256)
void softmax_rows(const float* __restrict__ part, const float* __restrict__ u2,
                  const float* __restrict__ bq, const float* __restrict__ bk,
                  const float* __restrict__ w,
                  float* __restrict__ P, _Float16* __restrict__ PT) {
    const int a = blockIdx.x;
    const int t = threadIdx.x;
    __shared__ float red[8];
    const size_t off = (size_t)a * 1024 + t * 4;
    f32x4 s = {};
#pragma unroll
    for (int z = 0; z < 4; ++z) {
        f32x4 v = *(const f32x4*)(part + (size_t)z * 1048576 + off);
        s[0] += v[0]; s[1] += v[1]; s[2] += v[2]; s[3] += v[3];
    }
    const float ru = u2[a], rb = bq[a];
    f32x4 bk4 = *(const f32x4*)(bk + t * 4);
    f32x4 w4 = *(const f32x4*)(w + t * 4);
#pragma unroll
    for (int j = 0; j < 4; ++j) s[j] = (s[j] + ru * bk4[j] + rb * w4[j]) * 0.03125f;

    float m = fmaxf(fmaxf(s[0], s[1]), fmaxf(s[2], s[3]));
    for (int o = 32; o; o >>= 1) m = fmaxf(m, __shfl_xor(m, o));
    if ((t & 63) == 0) red[t >> 6] = m;
    __syncthreads();
    m = fmaxf(fmaxf(red[0], red[1]), fmaxf(red[2], red[3]));

    float e0 = expf(s[0] - m), e1 = expf(s[1] - m);
    float e2 = expf(s[2] - m), e3 = expf(s[3] - m);
    float sum = e0 + e1 + e2 + e3;
    for (int o = 32; o; o >>= 1) sum += __shfl_xor(sum, o);
    if ((t & 63) == 0) red[4 + (t >> 6)] = sum;
    __syncthreads();
    sum = red[4] + red[5] + red[6] + red[7];
    const float inv = 1.0f / sum;

    f32x4 o4 = {e0 * inv, e1 * inv, e2 * inv, e3 * inv};
    *(f32x4*)(P + off) = o4;
    const int b = t * 4;
    PT[(size_t)(b + 0) * 1024 + a] = (_Float16)o4[0];
    PT[(size_t)(b + 1) * 1024 + a] = (_Float16)o4[1];
    PT[(size_t)(b + 2) * 1024 + a] = (_Float16)o4[2];
    PT[(size_t)(b + 3) * 1024 + a] = (_Float16)o4[3];
}

__global__ __launch_bounds__(256)
void attn_bv(const float* __restrict__ attn, const float* __restrict__ bv,
             float* __restrict__ c) {
    const int j = blockIdx.x * 256 + threadIdx.x;
    const int a0 = blockIdx.y * 64;
    float s = 0.f;
#pragma unroll 4
    for (int k = 0; k < 64; ++k) {
        const int a = a0 + k;
        s += attn[(size_t)a * 1024 + j] * bv[a];
    }
    atomicAdd(c + j, s);
}

extern "C" void kernel_launch(void* const* d_in, const int* in_sizes, int n_in,
                              void* d_out, int out_size, void* d_ws, size_t ws_size,
                              hipStream_t stream) {
    const float* x  = (const float*)d_in[0];
    const float* Wq = (const float*)d_in[1];
    const float* bq = (const float*)d_in[2];
    const float* Wk = (const float*)d_in[3];
    const float* bk = (const float*)d_in[4];
    const float* Wv = (const float*)d_in[5];
    const float* bv = (const float*)d_in[6];
    float* out  = (float*)d_out;                   // [S,D] fp32
    float* attn = out + (size_t)S_ * D_;           // [D,D] fp32

    char* ws = (char*)d_ws;
    float*    part  = (float*)ws;                          // 32MB, reused
    _Float16* partH = (_Float16*)ws;                       // G f16 partials
    _Float16* x16   = (_Float16*)(ws + 33554432);          // [S,D]   33.5MB
    _Float16* xT16  = (_Float16*)(ws + 67108864);          // [D,S]   33.5MB
    _Float16* wq16  = (_Float16*)(ws + 100663296);         // [D,D]   2MB
    _Float16* wk16  = (_Float16*)(ws + 102760448);
    _Float16* wvT16 = (_Float16*)(ws + 104857600);
    _Float16* G16   = (_Float16*)(ws + 106954752);
    _Float16* U16   = (_Float16*)(ws + 109051904);
    _Float16* PT    = (_Float16*)(ws + 111149056);
    _Float16* MT16  = (_Float16*)(ws + 113246208);
    float*    mvec  = (float*)(ws + 115343360);            // m, u2, w, c
    float*    u2    = mvec + 1024;
    float*    wv    = u2 + 1024;
    float*    cvec  = wv + 1024;

    zero_vec<<<16, 256, 0, stream>>>(mvec, 4096);
    cast_transpose<1, 1><<<dim3(16, 256), 256, 0, stream>>>(x, x16, xT16, mvec, S_);
    prep_w<<<1280, 256, 0, stream>>>(Wq, Wk, Wv, bq, mvec,
                                     wq16, wk16, wvT16, u2, wv);

    // G = xT * xT^T  (M=N=1024, K=16384, split-K 16, f16 partials)
    gemm256<<<256, 512, 0, stream>>>(xT16, xT16, partH,
                                     16384, 16384, 1024, 1024, 1048576LL,
                                     4, 16, 32);
    reduce_g<<<512, 256, 0, stream>>>(partH, G16);
    // U = Wq * G  (split-K4, counted-vmcnt engine)
    gemm_s128<<<dim3(8, 8, 4), 256, 0, stream>>>(wq16, G16, part,
                                                 1024, 1024, 1024, 256, 1048576);
    reduce_cast<<<1024, 256, 0, stream>>>(part, U16, 4, 1.0f);
    // scores partials = U * Wk^T (split-K4; rank-1 + scale fused in softmax)
    gemm_s128<<<dim3(8, 8, 4), 256, 0, stream>>>(U16, wk16, part,
                                                 1024, 1024, 1024, 256, 1048576);
    softmax_rows<<<1024, 256, 0, stream>>>(part, u2, bq, bk, wv, attn, PT);
    attn_bv<<<dim3(4, 16), 256, 0, stream>>>(attn, bv, cvec);
    // MT[j,i] = sum_a attn[a,j] Wv[a,i]  (split-K4)
    gemm_s128<<<dim3(8, 8, 4), 256, 0, stream>>>(PT, wvT16, part,
                                                 1024, 1024, 1024, 256, 1048576);
    reduce_cast<<<1024, 256, 0, stream>>>(part, MT16, 4, 1.0f);
    // out = x16 * MT^T + cvec  (M=16384, N=1024, K=1024; 1024 blocks, 2/CU)
    gemm128<<<1024, 256, 0, stream>>>(x16, MT16, out, cvec,
                                      1024, 1024, 1024, 1024, 8, 128);
}